// Round 1
// baseline (463.424 us; speedup 1.0000x reference)
//
#include <hip/hip_runtime.h>
#include <stdint.h>

typedef unsigned short u16;
typedef __attribute__((ext_vector_type(8))) short short8;
typedef __attribute__((ext_vector_type(8))) u16   u16x8;
typedef __attribute__((ext_vector_type(4))) u16   u16x4;
typedef __attribute__((ext_vector_type(4))) float f32x4;

#define B_DIM  8192
#define G_DIM  20000
#define H1_DIM 512
#define H2_DIM 256
#define P_DIM  128
#define A_DIM  64

union Frag { short8 s; u16x8 u; };

__device__ __forceinline__ u16 bf16_rne(float f) {
  uint32_t u = __float_as_uint(f);
  u += 0x7FFFu + ((u >> 16) & 1u);
  return (u16)(u >> 16);
}

__device__ __forceinline__ void gld16(const void* g, void* l) {
  __builtin_amdgcn_global_load_lds(
      (const __attribute__((address_space(1))) void*)g,
      (__attribute__((address_space(3))) void*)l, 16, 0, 0);
}

// ---------------- prep: f32 -> bf16 convert (vectorized) ----------------
__global__ void k_convert(const float* __restrict__ src, u16* __restrict__ dst, int n4) {
  int i = blockIdx.x * 256 + threadIdx.x;
  if (i >= n4) return;
  f32x4 v = ((const f32x4*)src)[i];
  u16x4 o;
  o[0] = bf16_rne(v[0]); o[1] = bf16_rne(v[1]);
  o[2] = bf16_rne(v[2]); o[3] = bf16_rne(v[3]);
  ((u16x4*)dst)[i] = o;
}

// ---------------- prep: W3[p][h][a] f32 -> W3T[p][a][h] bf16 ----------------
__global__ void k_transpose_w3(const float* __restrict__ W3, u16* __restrict__ W3T) {
  int idx = blockIdx.x * 256 + threadIdx.x;     // = (p*64+a)*256 + h
  if (idx >= P_DIM * H2_DIM * A_DIM) return;
  int h = idx & (H2_DIM - 1);
  int a = (idx >> 8) & (A_DIM - 1);
  int p = idx >> 14;
  W3T[idx] = bf16_rne(W3[((size_t)p * H2_DIM + h) * A_DIM + a]);
}

// ---------------- K1: layer-1 GEMM, split-K by 3, f32 partials ----------------
// C[m][n] partial = sum_k x[m][k]*W1b[n][k];  128x128 tile, BK=32, 4 waves 2x2.
__global__ __launch_bounds__(256, 3)
void k_gemm1(const float* __restrict__ X, const u16* __restrict__ W1b,
             float* __restrict__ partial) {
  const int m0 = blockIdx.x * 128;
  const int n0 = blockIdx.y * 128;
  const int ks = blockIdx.z;
  const int kt_begin = ks * 208 + (ks > 0 ? 1 : 0);   // splits {209,208,208} of 625 K-tiles
  const int nkt = (ks == 0) ? 209 : 208;

  const int tid  = threadIdx.x;
  const int lane = tid & 63;
  const int wid  = tid >> 6;
  const int wr = wid >> 1, wc = wid & 1;
  const int c15 = lane & 15, j4 = lane >> 4;

  __shared__ float lsA[2][128 * 32];   // f32 x-tile, rows 128B (8 slots), swz ^(row&7)
  __shared__ u16   lsB[2][128 * 32];   // bf16 W1-tile, rows 64B (4 slots), swz ^((row>>1)&3)

  f32x4 zero = {0.f, 0.f, 0.f, 0.f};
  f32x4 acc[4][4];
#pragma unroll
  for (int m = 0; m < 4; ++m)
#pragma unroll
    for (int n = 0; n < 4; ++n) acc[m][n] = zero;

  auto stage = [&](int buf, int kt) {
    const int k0 = kt * 32;
#pragma unroll
    for (int c = 0; c < 4; ++c) {                 // A: 16KB = 4 calls x 256thr x 16B
      int lin = c * 256 + tid;
      int row = lin >> 3, slot = lin & 7;
      int gslot = slot ^ (row & 7);
      gld16(X + (size_t)(m0 + row) * G_DIM + k0 + gslot * 4, &lsA[buf][lin * 4]);
    }
#pragma unroll
    for (int c = 0; c < 2; ++c) {                 // B: 8KB = 2 calls
      int lin = c * 256 + tid;
      int row = lin >> 2, slot = lin & 3;
      int gslot = slot ^ ((row >> 1) & 3);
      gld16(W1b + (size_t)(n0 + row) * G_DIM + k0 + gslot * 8, &lsB[buf][lin * 8]);
    }
  };

  stage(0, kt_begin);
  __syncthreads();
  int buf = 0;
  for (int t = 0; t < nkt; ++t) {
    if (t + 1 < nkt) stage(buf ^ 1, kt_begin + t + 1);

    Frag bfr[4];
#pragma unroll
    for (int n = 0; n < 4; ++n) {
      int row = wc * 64 + n * 16 + c15;
      int slot = j4 ^ ((row >> 1) & 3);
      bfr[n].s = *(const short8*)&lsB[buf][row * 32 + slot * 8];
    }
    Frag afr[4];
#pragma unroll
    for (int m = 0; m < 4; ++m) {
      int row = wr * 64 + m * 16 + c15;
      int s0 = (j4 * 2) ^ (row & 7);
      int s1 = (j4 * 2 + 1) ^ (row & 7);
      f32x4 f0 = *(const f32x4*)&lsA[buf][row * 32 + s0 * 4];
      f32x4 f1 = *(const f32x4*)&lsA[buf][row * 32 + s1 * 4];
#pragma unroll
      for (int i = 0; i < 4; ++i) {
        afr[m].u[i]     = bf16_rne(f0[i]);
        afr[m].u[i + 4] = bf16_rne(f1[i]);
      }
    }
#pragma unroll
    for (int m = 0; m < 4; ++m)
#pragma unroll
      for (int n = 0; n < 4; ++n)
        acc[m][n] = __builtin_amdgcn_mfma_f32_16x16x32_bf16(afr[m].s, bfr[n].s, acc[m][n], 0, 0, 0);

    __syncthreads();
    buf ^= 1;
  }

  float* outp = partial + ((size_t)ks * B_DIM + m0) * H1_DIM + n0;
#pragma unroll
  for (int m = 0; m < 4; ++m)
#pragma unroll
    for (int n = 0; n < 4; ++n)
#pragma unroll
      for (int r = 0; r < 4; ++r) {
        int row = wr * 64 + m * 16 + j4 * 4 + r;
        int col = wc * 64 + n * 16 + c15;
        outp[(size_t)row * H1_DIM + col] = acc[m][n][r];
      }
}

// ---------------- K1b: sum partials + bias + relu -> h1 bf16 ----------------
__global__ void k_reduce1(const float* __restrict__ partial, const float* __restrict__ b1,
                          u16* __restrict__ h1b) {
  const int n4 = B_DIM * H1_DIM / 4;
  int i = blockIdx.x * 256 + threadIdx.x;
  if (i >= n4) return;
  const f32x4* p0 = (const f32x4*)partial;
  const f32x4* p1 = p0 + n4;
  const f32x4* p2 = p1 + n4;
  f32x4 v0 = p0[i], v1 = p1[i], v2 = p2[i];
  f32x4 bb = ((const f32x4*)b1)[i & (H1_DIM / 4 - 1)];
  u16x4 o;
#pragma unroll
  for (int j = 0; j < 4; ++j)
    o[j] = bf16_rne(fmaxf(v0[j] + v1[j] + v2[j] + bb[j], 0.f));
  ((u16x4*)h1b)[i] = o;
}

// ---------------- K2: layer-2 GEMM bf16, bias+relu fused -> h2 bf16 ----------------
// 128x64 tile, BK=32, waves 2x2 (64x32 each)
__global__ __launch_bounds__(256, 2)
void k_gemm2(const u16* __restrict__ h1b, const u16* __restrict__ W2b,
             const float* __restrict__ b2, u16* __restrict__ h2b) {
  const int m0 = blockIdx.x * 128;
  const int n0 = blockIdx.y * 64;
  const int tid  = threadIdx.x;
  const int lane = tid & 63;
  const int wid  = tid >> 6;
  const int wr = wid >> 1, wc = wid & 1;
  const int c15 = lane & 15, j4 = lane >> 4;

  __shared__ u16 lsA[2][128 * 32];   // rows 64B, swz ^((row>>1)&3)
  __shared__ u16 lsB[2][64 * 32];

  f32x4 zero = {0.f, 0.f, 0.f, 0.f};
  f32x4 acc[4][2];
#pragma unroll
  for (int m = 0; m < 4; ++m) { acc[m][0] = zero; acc[m][1] = zero; }

  auto stage = [&](int buf, int kt) {
    const int k0 = kt * 32;
#pragma unroll
    for (int c = 0; c < 2; ++c) {
      int lin = c * 256 + tid;
      int row = lin >> 2, slot = lin & 3;
      int gslot = slot ^ ((row >> 1) & 3);
      gld16(h1b + (size_t)(m0 + row) * H1_DIM + k0 + gslot * 8, &lsA[buf][lin * 8]);
    }
    {
      int lin = tid;
      int row = lin >> 2, slot = lin & 3;
      int gslot = slot ^ ((row >> 1) & 3);
      gld16(W2b + (size_t)(n0 + row) * H1_DIM + k0 + gslot * 8, &lsB[buf][lin * 8]);
    }
  };

  stage(0, 0);
  __syncthreads();
  int buf = 0;
  const int nkt = H1_DIM / 32;   // 16
  for (int t = 0; t < nkt; ++t) {
    if (t + 1 < nkt) stage(buf ^ 1, t + 1);
    Frag bfr[2];
#pragma unroll
    for (int n = 0; n < 2; ++n) {
      int row = wc * 32 + n * 16 + c15;
      int slot = j4 ^ ((row >> 1) & 3);
      bfr[n].s = *(const short8*)&lsB[buf][row * 32 + slot * 8];
    }
    Frag afr[4];
#pragma unroll
    for (int m = 0; m < 4; ++m) {
      int row = wr * 64 + m * 16 + c15;
      int slot = j4 ^ ((row >> 1) & 3);
      afr[m].s = *(const short8*)&lsA[buf][row * 32 + slot * 8];
    }
#pragma unroll
    for (int m = 0; m < 4; ++m)
#pragma unroll
      for (int n = 0; n < 2; ++n)
        acc[m][n] = __builtin_amdgcn_mfma_f32_16x16x32_bf16(afr[m].s, bfr[n].s, acc[m][n], 0, 0, 0);
    __syncthreads();
    buf ^= 1;
  }

  float b2v[2];
  b2v[0] = b2[n0 + wc * 32 + c15];
  b2v[1] = b2[n0 + wc * 32 + 16 + c15];
#pragma unroll
  for (int m = 0; m < 4; ++m)
#pragma unroll
    for (int n = 0; n < 2; ++n)
#pragma unroll
      for (int r = 0; r < 4; ++r) {
        int row = m0 + wr * 64 + m * 16 + j4 * 4 + r;
        int col = n0 + wc * 32 + n * 16 + c15;
        h2b[(size_t)row * H2_DIM + col] = bf16_rne(fmaxf(acc[m][n][r] + b2v[n], 0.f));
      }
}

// ---------------- K3: fused heads: a=relu(h2@W3T[p]+b3); out=a.W4[p]+b4 ----------------
// block: 128 B-rows x 2 heads; waves 2x2 (wc selects head), BK=64, K=256
__global__ __launch_bounds__(256, 2)
void k_heads(const u16* __restrict__ h2b, const u16* __restrict__ W3T,
             const float* __restrict__ b3, const float* __restrict__ W4,
             const float* __restrict__ b4, float* __restrict__ out) {
  const int m0 = blockIdx.x * 128;
  const int p0 = blockIdx.y * 2;
  const int tid  = threadIdx.x;
  const int lane = tid & 63;
  const int wid  = tid >> 6;
  const int wr = wid >> 1, wc = wid & 1;
  const int c15 = lane & 15, j4 = lane >> 4;

  __shared__ u16 lsA[2][128 * 64];   // h2 tile, rows 128B (8 slots), swz ^(row&7)
  __shared__ u16 lsB[2][128 * 64];   // W3T 2 heads (row = (p-p0)*64 + a)

  f32x4 zero = {0.f, 0.f, 0.f, 0.f};
  f32x4 acc[4][4];
#pragma unroll
  for (int m = 0; m < 4; ++m)
#pragma unroll
    for (int n = 0; n < 4; ++n) acc[m][n] = zero;

  auto stage = [&](int buf, int kt) {
    const int k0 = kt * 64;
#pragma unroll
    for (int c = 0; c < 4; ++c) {
      int lin = c * 256 + tid;
      int row = lin >> 3, slot = lin & 7;
      int gslot = slot ^ (row & 7);
      gld16(h2b + (size_t)(m0 + row) * H2_DIM + k0 + gslot * 8, &lsA[buf][lin * 8]);
    }
#pragma unroll
    for (int c = 0; c < 4; ++c) {
      int lin = c * 256 + tid;
      int row = lin >> 3, slot = lin & 7;
      int gslot = slot ^ (row & 7);
      gld16(W3T + ((size_t)(p0 * 64 + row)) * H2_DIM + k0 + gslot * 8, &lsB[buf][lin * 8]);
    }
  };

  stage(0, 0);
  __syncthreads();
  int buf = 0;
  const int nkt = H2_DIM / 64;   // 4
  for (int t = 0; t < nkt; ++t) {
    if (t + 1 < nkt) stage(buf ^ 1, t + 1);
#pragma unroll
    for (int kk = 0; kk < 2; ++kk) {
      Frag bfr[4];
#pragma unroll
      for (int n = 0; n < 4; ++n) {
        int row = wc * 64 + n * 16 + c15;
        int slot = (kk * 4 + j4) ^ (row & 7);
        bfr[n].s = *(const short8*)&lsB[buf][row * 64 + slot * 8];
      }
      Frag afr[4];
#pragma unroll
      for (int m = 0; m < 4; ++m) {
        int row = wr * 64 + m * 16 + c15;
        int slot = (kk * 4 + j4) ^ (row & 7);
        afr[m].s = *(const short8*)&lsA[buf][row * 64 + slot * 8];
      }
#pragma unroll
      for (int m = 0; m < 4; ++m)
#pragma unroll
        for (int n = 0; n < 4; ++n)
          acc[m][n] = __builtin_amdgcn_mfma_f32_16x16x32_bf16(afr[m].s, bfr[n].s, acc[m][n], 0, 0, 0);
    }
    __syncthreads();
    buf ^= 1;
  }

  const int p = p0 + wc;
  float w4v[4], b3v[4];
#pragma unroll
  for (int n = 0; n < 4; ++n) {
    w4v[n] = W4[p * A_DIM + n * 16 + c15];
    b3v[n] = b3[p * A_DIM + n * 16 + c15];
  }
  const float b4v = b4[p];

  float s[4][4];
#pragma unroll
  for (int m = 0; m < 4; ++m)
#pragma unroll
    for (int r = 0; r < 4; ++r) s[m][r] = 0.f;
#pragma unroll
  for (int m = 0; m < 4; ++m)
#pragma unroll
    for (int n = 0; n < 4; ++n)
#pragma unroll
      for (int r = 0; r < 4; ++r) {
        float v = fmaxf(acc[m][n][r] + b3v[n], 0.f);
        s[m][r] += v * w4v[n];
      }
#pragma unroll
  for (int m = 0; m < 4; ++m)
#pragma unroll
    for (int r = 0; r < 4; ++r) {
      float v = s[m][r];
      v += __shfl_xor(v, 1);
      v += __shfl_xor(v, 2);
      v += __shfl_xor(v, 4);
      v += __shfl_xor(v, 8);
      s[m][r] = v;
    }
  if (c15 == 0) {
#pragma unroll
    for (int m = 0; m < 4; ++m)
#pragma unroll
      for (int r = 0; r < 4; ++r) {
        int row = m0 + wr * 64 + m * 16 + j4 * 4 + r;
        out[(size_t)row * P_DIM + p] = s[m][r] + b4v;
      }
  }
}

extern "C" void kernel_launch(void* const* d_in, const int* in_sizes, int n_in,
                              void* d_out, int out_size, void* d_ws, size_t ws_size,
                              hipStream_t stream) {
  const float* x  = (const float*)d_in[0];
  const float* W1 = (const float*)d_in[1];
  const float* b1 = (const float*)d_in[2];
  const float* W2 = (const float*)d_in[3];
  const float* b2 = (const float*)d_in[4];
  const float* W3 = (const float*)d_in[5];
  const float* b3 = (const float*)d_in[6];
  const float* W4 = (const float*)d_in[7];
  const float* b4 = (const float*)d_in[8];
  float* out = (float*)d_out;

  char* ws = (char*)d_ws;
  u16*   W1b  = (u16*)(ws);                    // 20,480,000 B
  u16*   W2b  = (u16*)(ws + 20480000);         //    262,144 B
  u16*   W3T  = (u16*)(ws + 20742144);         //  4,194,304 B
  u16*   h1b  = (u16*)(ws + 24936448);         //  8,388,608 B
  u16*   h2b  = (u16*)(ws + 33325056);         //  4,194,304 B
  float* part = (float*)(ws + 37519360);       // 50,331,648 B  (end ~87.9 MB)

  k_convert<<<dim3(10240000 / 4 / 256), dim3(256), 0, stream>>>(W1, W1b, 10240000 / 4);
  k_convert<<<dim3(131072 / 4 / 256), dim3(256), 0, stream>>>(W2, W2b, 131072 / 4);
  k_transpose_w3<<<dim3(2097152 / 256), dim3(256), 0, stream>>>(W3, W3T);

  k_gemm1<<<dim3(64, 4, 3), dim3(256), 0, stream>>>(x, W1b, part);
  k_reduce1<<<dim3(B_DIM * H1_DIM / 4 / 256), dim3(256), 0, stream>>>(part, b1, h1b);
  k_gemm2<<<dim3(64, 4), dim3(256), 0, stream>>>(h1b, W2b, b2, h2b);
  k_heads<<<dim3(64, 64), dim3(256), 0, stream>>>(h2b, W3T, b3, W4, b4, out);
}